// Round 1
// baseline (27.246 us; speedup 1.0000x reference)
//
#include <hip/hip_runtime.h>

#define NS 128   // samples per ray
#define NF 32    // features

// One wave (64 lanes) per ray. Block = 256 threads = 4 rays.
__global__ __launch_bounds__(256)
void volren_kernel(const float* __restrict__ depths,   // [n_rays, NS]
                   const float* __restrict__ sigma,    // [n_rays, NS]
                   const float* __restrict__ feats,    // [n_rays, NS, NF]
                   const int*   __restrict__ valid,    // [n_rays]
                   float* __restrict__ out_feats,      // [n_rays, NF]
                   float* __restrict__ out_depth,      // [n_rays]
                   float* __restrict__ out_ws,         // [n_rays]
                   float* __restrict__ out_alpha,      // [n_rays]
                   int n_rays)
{
    __shared__ float lds_w[4 * NS];   // 4 waves/block * 128 weights
    const int wave = threadIdx.x >> 6;
    const int lane = threadIdx.x & 63;
    const int ray  = blockIdx.x * 4 + wave;
    if (ray >= n_rays) return;

    const float* dptr = depths + (size_t)ray * NS;
    const float* sptr = sigma  + (size_t)ray * NS;

    // ---------- phase 1: per-sample free energy + wave-wide inclusive scan ----------
    // lane owns samples s_lo = lane and s_hi = lane + 64
    float d_lo   = dptr[lane];
    float d_lo_n = dptr[lane + 1];            // lane+1 <= 64, always in range
    float d_hi   = dptr[lane + 64];
    float d_hi_n = (lane < 63) ? dptr[lane + 65] : d_hi;  // last dist = 0
    float s_lo   = sptr[lane];
    float s_hi   = sptr[lane + 64];

    float fe_lo = (d_lo_n - d_lo) * s_lo;
    float fe_hi = (d_hi_n - d_hi) * s_hi;

    // inclusive scan across 64 lanes, chunk 0
    float c_lo = fe_lo;
    #pragma unroll
    for (int off = 1; off < 64; off <<= 1) {
        float t = __shfl_up(c_lo, off, 64);
        if (lane >= off) c_lo += t;
    }
    float tot_lo = __shfl(c_lo, 63, 64);
    // chunk 1
    float c_hi = fe_hi;
    #pragma unroll
    for (int off = 1; off < 64; off <<= 1) {
        float t = __shfl_up(c_hi, off, 64);
        if (lane >= off) c_hi += t;
    }
    c_hi += tot_lo;

    // w = alpha * exp(fe - cum) = exp(fe - cum) - exp(-cum)
    float w_lo = expf(fe_lo - c_lo) - expf(-c_lo);
    float w_hi = expf(fe_hi - c_hi) - expf(-c_hi);
    float a_lo = 1.0f - expf(-fe_lo);
    float a_hi = 1.0f - expf(-fe_hi);

    lds_w[wave * NS + lane]      = w_lo;
    lds_w[wave * NS + lane + 64] = w_hi;

    // scalar reductions: depth, alpha, weight-sum
    float dsum = w_lo * d_lo + w_hi * d_hi;
    float asum = w_lo * a_lo + w_hi * a_hi;
    float wsum = w_lo + w_hi;
    #pragma unroll
    for (int m = 1; m < 64; m <<= 1) {
        dsum += __shfl_xor(dsum, m, 64);
        asum += __shfl_xor(asum, m, 64);
        wsum += __shfl_xor(wsum, m, 64);
    }

    const float maskf = valid[ray] ? 1.0f : 0.0f;
    if (lane == 0) {
        out_depth[ray] = dsum * maskf;
        out_ws[ray]    = wsum * maskf;
        out_alpha[ray] = asum * maskf;
    }

    __syncthreads();   // make this wave's LDS weights visible (cheap, uniform)

    // ---------- phase 2: feats contraction ----------
    // lane = 8*j + q : sample-sub j in [0,8), float4 quad q in [0,8)
    // per iteration the wave reads 8 samples * 32 floats = 1 KiB contiguous
    const float4* fptr = (const float4*)(feats + (size_t)ray * NS * NF);
    const int j = lane >> 3;
    const int q = lane & 7;
    float4 acc = make_float4(0.f, 0.f, 0.f, 0.f);
    #pragma unroll
    for (int it = 0; it < NS / 8; ++it) {
        const int s = it * 8 + j;
        const float w = lds_w[wave * NS + s];  // 8 addrs x 8-lane broadcast: conflict-free
        const float4 v = fptr[s * 8 + q];
        acc.x += w * v.x;
        acc.y += w * v.y;
        acc.z += w * v.z;
        acc.w += w * v.w;
    }
    // reduce across the 8 sample-sub lanes (stride 8)
    #pragma unroll
    for (int m = 8; m < 64; m <<= 1) {
        acc.x += __shfl_xor(acc.x, m, 64);
        acc.y += __shfl_xor(acc.y, m, 64);
        acc.z += __shfl_xor(acc.z, m, 64);
        acc.w += __shfl_xor(acc.w, m, 64);
    }
    if (j == 0) {
        float4 o = make_float4(acc.x * maskf, acc.y * maskf, acc.z * maskf, acc.w * maskf);
        ((float4*)(out_feats + (size_t)ray * NF))[q] = o;
    }
}

extern "C" void kernel_launch(void* const* d_in, const int* in_sizes, int n_in,
                              void* d_out, int out_size, void* d_ws, size_t ws_size,
                              hipStream_t stream) {
    const float* depths = (const float*)d_in[0];   // sampled_depths [B,R,S]
    const float* sigma  = (const float*)d_in[1];   // sigma          [B,R,S]
    const float* feats  = (const float*)d_in[2];   // feats          [B,R,S,F]
    // d_in[3] = max_depths (unused by the reference math)
    const int*   valid  = (const int*)d_in[4];     // valid_rays     [B,R]

    const int n_rays = in_sizes[4];                // B*R = 8192

    float* out       = (float*)d_out;
    float* out_feats = out;                               // [n_rays, NF]
    float* out_depth = out + (size_t)n_rays * NF;         // [n_rays]
    float* out_ws    = out_depth + n_rays;                // [n_rays]
    float* out_alpha = out_ws + n_rays;                   // [n_rays]

    const int grid = (n_rays + 3) / 4;   // 4 rays (waves) per block
    volren_kernel<<<grid, 256, 0, stream>>>(depths, sigma, feats, valid,
                                            out_feats, out_depth, out_ws,
                                            out_alpha, n_rays);
}

// Round 2
// 26.423 us; speedup vs baseline: 1.0312x; 1.0312x over previous
//
#include <hip/hip_runtime.h>

#define NS 128   // samples per ray
#define NF 32    // features

// One wave (64 lanes) per ray. Block = 256 threads = 4 rays. No LDS, no barriers.
__global__ __launch_bounds__(256, 4)
void volren_kernel(const float* __restrict__ depths,   // [n_rays, NS]
                   const float* __restrict__ sigma,    // [n_rays, NS]
                   const float* __restrict__ feats,    // [n_rays, NS, NF]
                   const int*   __restrict__ valid,    // [n_rays]
                   float* __restrict__ out_feats,      // [n_rays, NF]
                   float* __restrict__ out_depth,      // [n_rays]
                   float* __restrict__ out_ws,         // [n_rays]
                   float* __restrict__ out_alpha,      // [n_rays]
                   int n_rays)
{
    const int wave = threadIdx.x >> 6;
    const int lane = threadIdx.x & 63;
    const int ray  = blockIdx.x * 4 + wave;
    if (ray >= n_rays) return;

    // ---------- issue the feats stream FIRST (93% of all bytes) ----------
    // lane = 8*j + q : sample-sub j in [0,8), float4 quad q in [0,8)
    // per unrolled step the wave reads 8 samples * 32 floats = 1 KiB contiguous
    const float4* fptr = (const float4*)(feats + (size_t)ray * NS * NF);
    const int j = lane >> 3;
    const int q = lane & 7;
    float4 v[16];
    #pragma unroll
    for (int it = 0; it < 16; ++it)
        v[it] = fptr[(it * 8 + j) * 8 + q];     // static indices -> registers

    // ---------- phase 1: free energy + wave-wide inclusive scan ----------
    // lane owns samples s_lo = lane and s_hi = lane + 64
    const float* dptr = depths + (size_t)ray * NS;
    const float* sptr = sigma  + (size_t)ray * NS;
    float d_lo = dptr[lane];
    float d_hi = dptr[lane + 64];
    float s_lo = sptr[lane];
    float s_hi = sptr[lane + 64];

    // next-sample depths via neighbor shuffle (no extra global loads)
    float d_lo_nb = __shfl(d_lo, (lane + 1) & 63, 64);
    float d_hi_nb = __shfl(d_hi, (lane + 1) & 63, 64);
    float d64     = __shfl(d_hi, 0, 64);
    float d_lo_n  = (lane == 63) ? d64  : d_lo_nb;
    float d_hi_n  = (lane == 63) ? d_hi : d_hi_nb;   // last dist = 0

    float fe_lo = (d_lo_n - d_lo) * s_lo;
    float fe_hi = (d_hi_n - d_hi) * s_hi;

    // inclusive scan across 64 lanes, chunk 0
    float c_lo = fe_lo;
    #pragma unroll
    for (int off = 1; off < 64; off <<= 1) {
        float t = __shfl_up(c_lo, off, 64);
        if (lane >= off) c_lo += t;
    }
    float tot_lo = __shfl(c_lo, 63, 64);
    // chunk 1
    float c_hi = fe_hi;
    #pragma unroll
    for (int off = 1; off < 64; off <<= 1) {
        float t = __shfl_up(c_hi, off, 64);
        if (lane >= off) c_hi += t;
    }
    c_hi += tot_lo;

    // w = alpha * exp(fe - cum) = exp(fe - cum) - exp(-cum)
    float w_lo = expf(fe_lo - c_lo) - expf(-c_lo);
    float w_hi = expf(fe_hi - c_hi) - expf(-c_hi);
    float a_lo = 1.0f - expf(-fe_lo);
    float a_hi = 1.0f - expf(-fe_hi);

    // scalar reductions: depth, alpha, weight-sum
    float dsum = w_lo * d_lo + w_hi * d_hi;
    float asum = w_lo * a_lo + w_hi * a_hi;
    float wsum = w_lo + w_hi;
    #pragma unroll
    for (int m = 1; m < 64; m <<= 1) {
        dsum += __shfl_xor(dsum, m, 64);
        asum += __shfl_xor(asum, m, 64);
        wsum += __shfl_xor(wsum, m, 64);
    }

    const float maskf = valid[ray] ? 1.0f : 0.0f;
    if (lane == 0) {
        out_depth[ray] = dsum * maskf;
        out_ws[ray]    = wsum * maskf;
        out_alpha[ray] = asum * maskf;
    }

    // ---------- phase 2: feats contraction (weights via in-wave shuffle) ----------
    float4 acc = make_float4(0.f, 0.f, 0.f, 0.f);
    #pragma unroll
    for (int it = 0; it < 16; ++it) {
        const int s = it * 8 + j;                     // sample index for this lane
        const float w = (it < 8) ? __shfl(w_lo, s, 64)
                                 : __shfl(w_hi, s - 64, 64);  // branch is compile-time
        acc.x += w * v[it].x;
        acc.y += w * v[it].y;
        acc.z += w * v[it].z;
        acc.w += w * v[it].w;
    }
    // reduce across the 8 sample-sub lanes (stride 8)
    #pragma unroll
    for (int m = 8; m < 64; m <<= 1) {
        acc.x += __shfl_xor(acc.x, m, 64);
        acc.y += __shfl_xor(acc.y, m, 64);
        acc.z += __shfl_xor(acc.z, m, 64);
        acc.w += __shfl_xor(acc.w, m, 64);
    }
    if (j == 0) {
        float4 o = make_float4(acc.x * maskf, acc.y * maskf, acc.z * maskf, acc.w * maskf);
        ((float4*)(out_feats + (size_t)ray * NF))[q] = o;
    }
}

extern "C" void kernel_launch(void* const* d_in, const int* in_sizes, int n_in,
                              void* d_out, int out_size, void* d_ws, size_t ws_size,
                              hipStream_t stream) {
    const float* depths = (const float*)d_in[0];   // sampled_depths [B,R,S]
    const float* sigma  = (const float*)d_in[1];   // sigma          [B,R,S]
    const float* feats  = (const float*)d_in[2];   // feats          [B,R,S,F]
    // d_in[3] = max_depths (unused by the reference math)
    const int*   valid  = (const int*)d_in[4];     // valid_rays     [B,R]

    const int n_rays = in_sizes[4];                // B*R = 8192

    float* out       = (float*)d_out;
    float* out_feats = out;                               // [n_rays, NF]
    float* out_depth = out + (size_t)n_rays * NF;         // [n_rays]
    float* out_ws    = out_depth + n_rays;                // [n_rays]
    float* out_alpha = out_ws + n_rays;                   // [n_rays]

    const int grid = (n_rays + 3) / 4;   // 4 rays (waves) per block
    volren_kernel<<<grid, 256, 0, stream>>>(depths, sigma, feats, valid,
                                            out_feats, out_depth, out_ws,
                                            out_alpha, n_rays);
}

// Round 3
// 26.128 us; speedup vs baseline: 1.0428x; 1.0113x over previous
//
#include <hip/hip_runtime.h>

#define NS 128   // samples per ray
#define NF 32    // features

// One wave (64 lanes) per ray. Block = 256 threads = 4 rays. No LDS, no barriers.
// Load order exploits in-order vmcnt retirement: small depth/sigma loads FIRST
// (scan needs them), then feats chunk 0; the serial scan overlaps chunk-0 flight.
__global__ __launch_bounds__(256)
void volren_kernel(const float* __restrict__ depths,   // [n_rays, NS]
                   const float* __restrict__ sigma,    // [n_rays, NS]
                   const float* __restrict__ feats,    // [n_rays, NS, NF]
                   const int*   __restrict__ valid,    // [n_rays]
                   float* __restrict__ out_feats,      // [n_rays, NF]
                   float* __restrict__ out_depth,      // [n_rays]
                   float* __restrict__ out_ws,         // [n_rays]
                   float* __restrict__ out_alpha,      // [n_rays]
                   int n_rays)
{
    const int wave = threadIdx.x >> 6;
    const int lane = threadIdx.x & 63;
    const int ray  = blockIdx.x * 4 + wave;
    if (ray >= n_rays) return;

    // ---------- issue the scan's inputs FIRST (needed earliest; vmcnt is in-order) ----------
    const float* dptr = depths + (size_t)ray * NS;
    const float* sptr = sigma  + (size_t)ray * NS;
    float d_lo = dptr[lane];
    float d_hi = dptr[lane + 64];
    float s_lo = sptr[lane];
    float s_hi = sptr[lane + 64];

    // ---------- issue feats chunk 0 (8 x float4 / lane = 8 KiB / wave) ----------
    // lane = 8*j + q : sample-sub j in [0,8), float4 quad q in [0,8)
    const float4* fptr = (const float4*)(feats + (size_t)ray * NS * NF);
    const int j = lane >> 3;
    const int q = lane & 7;
    float4 v0[8];
    #pragma unroll
    for (int it = 0; it < 8; ++it)
        v0[it] = fptr[(it * 8 + j) * 8 + q];

    // ---------- phase 1: free energy + wave-wide inclusive scan (overlaps chunk-0 flight) ----------
    float d_lo_nb = __shfl(d_lo, (lane + 1) & 63, 64);
    float d_hi_nb = __shfl(d_hi, (lane + 1) & 63, 64);
    float d64     = __shfl(d_hi, 0, 64);
    float d_lo_n  = (lane == 63) ? d64  : d_lo_nb;
    float d_hi_n  = (lane == 63) ? d_hi : d_hi_nb;   // last dist = 0

    float fe_lo = (d_lo_n - d_lo) * s_lo;
    float fe_hi = (d_hi_n - d_hi) * s_hi;

    float c_lo = fe_lo;
    #pragma unroll
    for (int off = 1; off < 64; off <<= 1) {
        float t = __shfl_up(c_lo, off, 64);
        if (lane >= off) c_lo += t;
    }
    float tot_lo = __shfl(c_lo, 63, 64);
    float c_hi = fe_hi;
    #pragma unroll
    for (int off = 1; off < 64; off <<= 1) {
        float t = __shfl_up(c_hi, off, 64);
        if (lane >= off) c_hi += t;
    }
    c_hi += tot_lo;

    // w = alpha * exp(fe - cum) = exp(fe - cum) - exp(-cum)
    float w_lo = expf(fe_lo - c_lo) - expf(-c_lo);
    float w_hi = expf(fe_hi - c_hi) - expf(-c_hi);
    float a_lo = 1.0f - expf(-fe_lo);
    float a_hi = 1.0f - expf(-fe_hi);

    // ---------- issue feats chunk 1 before consuming chunk 0 (pipeline) ----------
    float4 v1[8];
    #pragma unroll
    for (int it = 0; it < 8; ++it)
        v1[it] = fptr[((it + 8) * 8 + j) * 8 + q];

    // scalar reductions: depth, alpha, weight-sum
    float dsum = w_lo * d_lo + w_hi * d_hi;
    float asum = w_lo * a_lo + w_hi * a_hi;
    float wsum = w_lo + w_hi;
    #pragma unroll
    for (int m = 1; m < 64; m <<= 1) {
        dsum += __shfl_xor(dsum, m, 64);
        asum += __shfl_xor(asum, m, 64);
        wsum += __shfl_xor(wsum, m, 64);
    }

    const float maskf = valid[ray] ? 1.0f : 0.0f;
    if (lane == 0) {
        out_depth[ray] = dsum * maskf;
        out_ws[ray]    = wsum * maskf;
        out_alpha[ray] = asum * maskf;
    }

    // ---------- phase 2: feats contraction (weights via in-wave shuffle) ----------
    float4 acc = make_float4(0.f, 0.f, 0.f, 0.f);
    #pragma unroll
    for (int it = 0; it < 8; ++it) {
        const float w = __shfl(w_lo, it * 8 + j, 64);
        acc.x += w * v0[it].x;
        acc.y += w * v0[it].y;
        acc.z += w * v0[it].z;
        acc.w += w * v0[it].w;
    }
    #pragma unroll
    for (int it = 0; it < 8; ++it) {
        const float w = __shfl(w_hi, it * 8 + j, 64);
        acc.x += w * v1[it].x;
        acc.y += w * v1[it].y;
        acc.z += w * v1[it].z;
        acc.w += w * v1[it].w;
    }
    // reduce across the 8 sample-sub lanes (stride 8)
    #pragma unroll
    for (int m = 8; m < 64; m <<= 1) {
        acc.x += __shfl_xor(acc.x, m, 64);
        acc.y += __shfl_xor(acc.y, m, 64);
        acc.z += __shfl_xor(acc.z, m, 64);
        acc.w += __shfl_xor(acc.w, m, 64);
    }
    if (j == 0) {
        float4 o = make_float4(acc.x * maskf, acc.y * maskf, acc.z * maskf, acc.w * maskf);
        ((float4*)(out_feats + (size_t)ray * NF))[q] = o;
    }
}

extern "C" void kernel_launch(void* const* d_in, const int* in_sizes, int n_in,
                              void* d_out, int out_size, void* d_ws, size_t ws_size,
                              hipStream_t stream) {
    const float* depths = (const float*)d_in[0];   // sampled_depths [B,R,S]
    const float* sigma  = (const float*)d_in[1];   // sigma          [B,R,S]
    const float* feats  = (const float*)d_in[2];   // feats          [B,R,S,F]
    // d_in[3] = max_depths (unused by the reference math)
    const int*   valid  = (const int*)d_in[4];     // valid_rays     [B,R]

    const int n_rays = in_sizes[4];                // B*R = 8192

    float* out       = (float*)d_out;
    float* out_feats = out;                               // [n_rays, NF]
    float* out_depth = out + (size_t)n_rays * NF;         // [n_rays]
    float* out_ws    = out_depth + n_rays;                // [n_rays]
    float* out_alpha = out_ws + n_rays;                   // [n_rays]

    const int grid = (n_rays + 3) / 4;   // 4 rays (waves) per block
    volren_kernel<<<grid, 256, 0, stream>>>(depths, sigma, feats, valid,
                                            out_feats, out_depth, out_ws,
                                            out_alpha, n_rays);
}